// Round 3
// baseline (700.369 us; speedup 1.0000x reference)
//
#include <hip/hip_runtime.h>
#include <math.h>

#define HIDDEN 16
#define CIN 5
#define BB 8
#define TT 12
#define HH 256
#define WW 256
#define TX 32
#define TY 8
#define HALO_X 34
#define HALO_Y 10
#define NPX (HALO_X * HALO_Y)   // 340 staged pixels
#define STRIDE 40               // shorts per px row: 80 B = 20 banks -> conflict-free phases
#define NBLK_PERSIST 1024       // 4 blocks/CU x 256 CU; each owns 2 tiles
#define NTILES 2048

typedef __attribute__((ext_vector_type(8))) short bf16x8;   // 8 bf16 (4 VGPRs)
typedef __attribute__((ext_vector_type(4))) float floatx4;

__device__ __forceinline__ unsigned short f2bf(float f) {   // RNE fp32->bf16
    unsigned int u = __float_as_uint(f);
    u += 0x7fffu + ((u >> 16) & 1u);
    return (unsigned short)(u >> 16);
}
__device__ __forceinline__ float bf2f(unsigned short s) {
    return __uint_as_float(((unsigned int)s) << 16);
}
__device__ __forceinline__ float fast_sigmoid(float x) { return 1.0f / (1.0f + __expf(-x)); }
__device__ __forceinline__ float fast_tanh(float x) {
    float e2 = __expf(-2.0f * fabsf(x));
    float t = (1.0f - e2) / (1.0f + e2);
    return copysignf(t, x);
}

// Pack W_cell [64][21][3][3] into exact B-fragment layout for
// mfma_f32_16x16x32_bf16: Wfrag[tap][gate][lane][j]; lane holds
// B[k=(lane>>4)*8+j][col=lane&15], col = hidden unit, N-tile = gate.
// k-order: 0..15 = h units (ci_ref 5+k), 16..20 = x chans, 21..31 = 0.
__global__ void prep_w_kernel(const float* __restrict__ Wc,
                              unsigned short* __restrict__ Wfrag) {
    int i = blockIdx.x * 256 + threadIdx.x;
    if (i >= 9 * 4 * 64 * 8) return;
    int j    = i & 7;
    int lane = (i >> 3) & 63;
    int g    = (i >> 9) & 3;
    int tap  = i >> 11;
    int k    = ((lane >> 4) << 3) + j;
    int col  = lane & 15;
    int o    = g * 16 + col;
    float w  = 0.0f;
    if (k < 21) {
        int ci_ref = (k < 16) ? (5 + k) : (k - 16);
        w = Wc[(o * 21 + ci_ref) * 9 + tap];
    }
    Wfrag[i] = f2bf(w);
}

// One-time x repack: planar fp32 [b][t][c][y][x] -> channel-last bf16 [b][t][y][x][8]
__global__ void prep_x_kernel(const float* __restrict__ x,
                              unsigned short* __restrict__ xp) {
    size_t n = (size_t)blockIdx.x * 256 + threadIdx.x;
    const size_t TOTPX = (size_t)BB * TT * HH * WW;
    if (n >= TOTPX) return;
    size_t bt  = n / (size_t)(HH * WW);
    size_t pix = n - bt * (size_t)(HH * WW);
    const float* src = x + bt * (size_t)CIN * HH * WW + pix;
    unsigned short v[8];
    #pragma unroll
    for (int c = 0; c < CIN; ++c) v[c] = f2bf(src[(size_t)c * HH * WW]);
    v[5] = 0; v[6] = 0; v[7] = 0;
    *(uint4*)&xp[n * 8] = *(const uint4*)v;
}

__global__ void prep_flags_kernel(unsigned int* __restrict__ flags) {
    int i = blockIdx.x * 256 + threadIdx.x;
    if (i < NTILES) flags[i] = 0;
}

// ---------------------------------------------------------------------------
// Persistent cooperative kernel, NO grid.sync: tile-level producer/consumer
// flags. flag[n] = number of completed steps of tile n. Staging step t needs
// all 8 neighbors' flag >= t. h double-buffer is 1-step-skew safe under this
// protocol. c-state lives in registers; final 1x1 conv fused at t==TT-1.
// ---------------------------------------------------------------------------
__global__ __launch_bounds__(256, 4)
void convlstm_persistent_kernel(const float* __restrict__ x,
                                const unsigned short* __restrict__ xp,  // may be null
                                unsigned short* __restrict__ ha,
                                unsigned short* __restrict__ hbuf,
                                const unsigned short* __restrict__ Wfrag,
                                const float* __restrict__ bias,
                                const float* __restrict__ Wf,
                                const float* __restrict__ bfin,
                                float* __restrict__ out,
                                unsigned int* __restrict__ flags,
                                int use_xp) {
    __shared__ unsigned short tile[NPX * STRIDE];   // 27200 B

    const int tid  = threadIdx.x;
    const int lane = tid & 63;
    const int wave = tid >> 6;
    const int u    = lane & 15;
    const int quad = lane >> 4;
    const int bid  = (int)blockIdx.x;

    // ---- per-lane neighbor tile ids (wave0 lanes 0..7 poll), per tl ----
    int nb_id[2];
    unsigned nb_act = 0;
    {
        int s  = lane + (lane >= 4 ? 1 : 0);      // skip center
        int dy = s / 3 - 1;
        int dx = s - (s / 3) * 3 - 1;
        #pragma unroll
        for (int tl = 0; tl < 2; ++tl) {
            int n  = bid + tl * NBLK_PERSIST;
            int tx = n & 7;
            int ty = (n >> 3) & 31;
            bool act = (lane < 8) && (tx + dx >= 0) && (tx + dx < 8)
                                  && (ty + dy >= 0) && (ty + dy < 32);
            nb_id[tl] = act ? (n + dy * 8 + dx) : 0;
            if (act) nb_act |= 1u << tl;
        }
    }

    // ---- staging descriptors, hoisted out of the t loop ----
    // it=0: px index tid; it=1: px index tid+256 (valid if tid < NPX-256)
    int hof[2][2];     // elem offset into h (t-independent)
    int xof[2][2];     // elem offset into xp at t=0 (+ t*HH*WW*8 per step)
    int pixv[2][2];    // pixel index within image (for !use_xp fallback)
    int bbv[2];
    unsigned inbm = 0;
    #pragma unroll
    for (int tl = 0; tl < 2; ++tl) {
        int n  = bid + tl * NBLK_PERSIST;
        int x0 = (n & 7) * TX;
        int y0 = ((n >> 3) & 31) * TY;
        int bb = n >> 8;
        bbv[tl] = bb;
        #pragma unroll
        for (int it = 0; it < 2; ++it) {
            int i  = tid + it * 256;
            int ly = i / HALO_X;
            int lx = i - ly * HALO_X;
            int gy = y0 + ly - 1;
            int gx = x0 + lx - 1;
            bool inb = (gy >= 0 && gy < HH && gx >= 0 && gx < WW) && (i < NPX);
            int pix = gy * WW + gx;
            pixv[tl][it] = pix;
            hof[tl][it]  = (bb * HH * WW + pix) * HIDDEN;
            xof[tl][it]  = (bb * TT * HH * WW + pix) * 8;
            if (inb) inbm |= 1u << (tl * 2 + it);
        }
    }

    float bg[4];
    #pragma unroll
    for (int g = 0; g < 4; ++g) bg[g] = bias[g * 16 + u];
    const float wfu = Wf[u];
    const float bf0 = bfin[0];

    // c-state registers: [tl][mh][r] per half (static indexing only)
    float cA[2][2][4];
    float cB[2][2][4];
    #pragma unroll
    for (int a = 0; a < 2; ++a)
        #pragma unroll
        for (int m = 0; m < 2; ++m)
            #pragma unroll
            for (int r = 0; r < 4; ++r) { cA[a][m][r] = 0.0f; cB[a][m][r] = 0.0f; }

    #pragma unroll 1
    for (int t = 0; t < TT; ++t) {
        const unsigned short* h_in  = (t & 1) ? ha : hbuf;
        unsigned short*       h_out = (t & 1) ? hbuf : ha;
        const int first = (t == 0);
        const int last  = (t == TT - 1);

        #pragma unroll
        for (int tl = 0; tl < 2; ++tl) {
            const int n  = bid + tl * NBLK_PERSIST;   // 0..2047
            const int x0 = (n & 7) * TX;
            const int y0 = ((n >> 3) & 31) * TY;
            const int bb = bbv[tl];

            // ---- wait for the 8 neighbor tiles to have completed step t-1 ----
            if (t > 0) {
                if (wave == 0) {
                    const bool act = (nb_act >> tl) & 1;
                    const unsigned need = (unsigned)t;
                    for (;;) {
                        unsigned v = act
                            ? __hip_atomic_load(&flags[nb_id[tl]], __ATOMIC_RELAXED,
                                                __HIP_MEMORY_SCOPE_AGENT)
                            : 0xFFFFFFFFu;
                        if (__all(v >= need)) break;
                        __builtin_amdgcn_s_sleep(2);
                    }
                    if (tid == 0) __threadfence();   // acquire: inv L1/L2
                }
                __syncthreads();   // also protects LDS reuse
            } else if (tl == 1) {
                __syncthreads();   // LDS reuse protection at t==0
            }

            // ---- stage tile (precomputed descriptors) ----
            #pragma unroll
            for (int it = 0; it < 2; ++it) {
                if (it == 1 && tid >= NPX - 256) break;
                unsigned short* row = &tile[(tid + it * 256) * STRIDE];
                const bool inb = (inbm >> (tl * 2 + it)) & 1;
                uint4 z = {0, 0, 0, 0};
                if (inb && !first) {
                    const unsigned short* hp = h_in + hof[tl][it];
                    *(uint4*)&row[0] = *(const uint4*)&hp[0];
                    *(uint4*)&row[8] = *(const uint4*)&hp[8];
                } else {
                    *(uint4*)&row[0] = z;
                    *(uint4*)&row[8] = z;
                }
                if (use_xp) {
                    if (inb)
                        *(uint4*)&row[16] =
                            *(const uint4*)&xp[xof[tl][it] + t * (HH * WW * 8)];
                    else
                        *(uint4*)&row[16] = z;
                } else {
                    #pragma unroll
                    for (int ci = 0; ci < CIN; ++ci) {
                        float v = 0.0f;
                        if (inb) v = x[(((size_t)bb * TT + t) * CIN + ci) * (size_t)(HH * WW)
                                       + pixv[tl][it]];
                        row[16 + ci] = f2bf(v);
                    }
                    row[21] = 0; row[22] = 0; row[23] = 0;
                }
                *(uint4*)&row[24] = z;
            }
            __syncthreads();

            // ---- compute: 2 halves of 2 M-strips each ----
            #pragma unroll 1
            for (int half = 0; half < 2; ++half) {
                floatx4 acc[2][4];
                int abase[2];
                #pragma unroll
                for (int mh = 0; mh < 2; ++mh) {
                    int ml = half * 2 + mh;
                    int m  = wave + ml * 4;
                    int my = m >> 1;
                    int mx = (m & 1) << 4;
                    abase[mh] = (my * HALO_X + mx + u) * STRIDE + quad * 8;
                    #pragma unroll
                    for (int g = 0; g < 4; ++g)
                        acc[mh][g] = (floatx4){bg[g], bg[g], bg[g], bg[g]};
                }

                #pragma unroll 3
                for (int tap = 0; tap < 9; ++tap) {
                    int ky = tap / 3;
                    int kx = tap - ky * 3;
                    int toff = (ky * HALO_X + kx) * STRIDE;
                    bf16x8 bfr[4];
                    #pragma unroll
                    for (int g = 0; g < 4; ++g)
                        bfr[g] = *(const bf16x8*)&Wfrag[(size_t)((tap * 4 + g) * 64 + lane) * 8];
                    #pragma unroll
                    for (int mh = 0; mh < 2; ++mh) {
                        bf16x8 af = *(const bf16x8*)&tile[abase[mh] + toff];
                        #pragma unroll
                        for (int g = 0; g < 4; ++g)
                            acc[mh][g] = __builtin_amdgcn_mfma_f32_16x16x32_bf16(
                                af, bfr[g], acc[mh][g], 0, 0, 0);
                    }
                }

                // ---- epilogue: gates + register c update ----
                #pragma unroll
                for (int mh = 0; mh < 2; ++mh) {
                    int ml = half * 2 + mh;
                    int m  = wave + ml * 4;
                    int my = m >> 1;
                    int mx = (m & 1) << 4;
                    int py = y0 + my;
                    #pragma unroll
                    for (int r = 0; r < 4; ++r) {
                        int pxx = x0 + mx + quad * 4 + r;
                        float ig = fast_sigmoid(acc[mh][0][r]);
                        float fg = fast_sigmoid(acc[mh][1][r]);
                        float og = fast_sigmoid(acc[mh][2][r]);
                        float gg = fast_tanh(acc[mh][3][r]);
                        float c_old = half ? cB[tl][mh][r] : cA[tl][mh][r];
                        float c_new = fg * c_old + ig * gg;
                        if (half) cB[tl][mh][r] = c_new; else cA[tl][mh][r] = c_new;
                        float hval = og * fast_tanh(c_new);
                        if (last) {
                            float s = wfu * hval;
                            s += __shfl_xor(s, 1);
                            s += __shfl_xor(s, 2);
                            s += __shfl_xor(s, 4);
                            s += __shfl_xor(s, 8);
                            if (u == 0)
                                out[(size_t)bb * HH * WW + (size_t)py * WW + pxx] = s + bf0;
                        } else {
                            size_t idx = ((size_t)bb * HH * WW + (size_t)py * WW + pxx)
                                         * HIDDEN + u;
                            h_out[idx] = f2bf(hval);
                        }
                    }
                }
            }

            // ---- publish: release h stores, bump flag ----
            if (!last) {
                __syncthreads();   // drains all waves' vmcnt before s_barrier
                if (tid == 0) {
                    __threadfence();   // release: wb L2 -> visible device-wide
                    __hip_atomic_store(&flags[n], (unsigned)(t + 1), __ATOMIC_RELAXED,
                                       __HIP_MEMORY_SCOPE_AGENT);
                }
            }
        }
    }
}

// ---------------------------------------------------------------------------
// Legacy per-step path (round-0, proven) — fallback if cooperative launch
// is unavailable.
// ---------------------------------------------------------------------------
__global__ __launch_bounds__(256, 5)
void convlstm_step_kernel(const float* __restrict__ x, int t,
                          const unsigned short* __restrict__ xp,  // may be null
                          const unsigned short* __restrict__ h_in,
                          unsigned short* __restrict__ h_out,
                          float* __restrict__ c_state,
                          const unsigned short* __restrict__ Wfrag,
                          const float* __restrict__ bias,
                          int first, int use_xp) {
    __shared__ unsigned short tile[NPX * STRIDE];   // 27200 B

    const int tid  = threadIdx.x;
    const int lane = tid & 63;
    const int wave = tid >> 6;
    const int x0 = blockIdx.x * TX;
    const int y0 = blockIdx.y * TY;
    const int bb = blockIdx.z;

    for (int i = tid; i < NPX; i += 256) {
        int ly = i / HALO_X;
        int lx = i - ly * HALO_X;
        int gy = y0 + ly - 1;
        int gx = x0 + lx - 1;
        bool inb = (gy >= 0 && gy < HH && gx >= 0 && gx < WW);
        unsigned short* row = &tile[i * STRIDE];
        uint4 z = {0, 0, 0, 0};
        if (inb && !first) {
            size_t hbase = ((size_t)bb * HH * WW + (size_t)gy * WW + gx) * HIDDEN;
            *(uint4*)&row[0] = *(const uint4*)&h_in[hbase];
            *(uint4*)&row[8] = *(const uint4*)&h_in[hbase + 8];
        } else {
            *(uint4*)&row[0] = z;
            *(uint4*)&row[8] = z;
        }
        if (use_xp) {
            if (inb) {
                size_t xb = (((size_t)bb * TT + t) * (size_t)(HH * WW)
                             + (size_t)gy * WW + gx) * 8;
                *(uint4*)&row[16] = *(const uint4*)&xp[xb];
            } else {
                *(uint4*)&row[16] = z;
            }
        } else {
            #pragma unroll
            for (int ci = 0; ci < CIN; ++ci) {
                float v = 0.0f;
                if (inb) v = x[(((size_t)bb * TT + t) * CIN + ci) * (size_t)(HH * WW)
                               + (size_t)gy * WW + gx];
                row[16 + ci] = f2bf(v);
            }
            row[21] = 0; row[22] = 0; row[23] = 0;
        }
        *(uint4*)&row[24] = z;
    }
    __syncthreads();

    const int u    = lane & 15;
    const int quad = lane >> 4;

    float bg[4];
    #pragma unroll
    for (int g = 0; g < 4; ++g) bg[g] = bias[g * 16 + u];

    #pragma unroll 1
    for (int half = 0; half < 2; ++half) {
        floatx4 acc[2][4];
        int abase[2];
        #pragma unroll
        for (int mh = 0; mh < 2; ++mh) {
            int ml = half * 2 + mh;
            int m  = wave + ml * 4;
            int my = m >> 1;
            int mx = (m & 1) << 4;
            abase[mh] = (my * HALO_X + mx + u) * STRIDE + quad * 8;
            #pragma unroll
            for (int g = 0; g < 4; ++g)
                acc[mh][g] = (floatx4){bg[g], bg[g], bg[g], bg[g]};
        }

        #pragma unroll 3
        for (int tap = 0; tap < 9; ++tap) {
            int ky = tap / 3;
            int kx = tap - ky * 3;
            int toff = (ky * HALO_X + kx) * STRIDE;
            bf16x8 bfr[4];
            #pragma unroll
            for (int g = 0; g < 4; ++g)
                bfr[g] = *(const bf16x8*)&Wfrag[(size_t)((tap * 4 + g) * 64 + lane) * 8];
            #pragma unroll
            for (int mh = 0; mh < 2; ++mh) {
                bf16x8 af = *(const bf16x8*)&tile[abase[mh] + toff];
                #pragma unroll
                for (int g = 0; g < 4; ++g)
                    acc[mh][g] = __builtin_amdgcn_mfma_f32_16x16x32_bf16(
                        af, bfr[g], acc[mh][g], 0, 0, 0);
            }
        }

        #pragma unroll
        for (int mh = 0; mh < 2; ++mh) {
            int ml = half * 2 + mh;
            int m  = wave + ml * 4;
            int my = m >> 1;
            int mx = (m & 1) << 4;
            int py = y0 + my;
            #pragma unroll
            for (int r = 0; r < 4; ++r) {
                int pxx = x0 + mx + quad * 4 + r;
                size_t idx = ((size_t)bb * HH * WW + (size_t)py * WW + pxx) * HIDDEN + u;
                float ig = fast_sigmoid(acc[mh][0][r]);
                float fg = fast_sigmoid(acc[mh][1][r]);
                float og = fast_sigmoid(acc[mh][2][r]);
                float gg = fast_tanh(acc[mh][3][r]);
                float c_old = first ? 0.0f : c_state[idx];
                float c_new = fg * c_old + ig * gg;
                c_state[idx] = c_new;
                h_out[idx] = f2bf(og * fast_tanh(c_new));
            }
        }
    }
}

// Final 1x1 conv from bf16 channel-last h (legacy path only)
__global__ void final_conv_kernel(const unsigned short* __restrict__ h,
                                  const float* __restrict__ Wf,
                                  const float* __restrict__ bf_,
                                  float* __restrict__ out) {
    int i = blockIdx.x * 256 + threadIdx.x;
    if (i >= BB * HH * WW) return;
    size_t base = (size_t)i * HIDDEN;
    uint4 v0 = *(const uint4*)&h[base];
    uint4 v1 = *(const uint4*)&h[base + 8];
    const unsigned short* p0 = (const unsigned short*)&v0;
    const unsigned short* p1 = (const unsigned short*)&v1;
    float s = bf_[0];
    #pragma unroll
    for (int k = 0; k < 8; ++k) s += Wf[k] * bf2f(p0[k]);
    #pragma unroll
    for (int k = 0; k < 8; ++k) s += Wf[8 + k] * bf2f(p1[k]);
    out[i] = s;
}

extern "C" void kernel_launch(void* const* d_in, const int* in_sizes, int n_in,
                              void* d_out, int out_size, void* d_ws, size_t ws_size,
                              hipStream_t stream) {
    const float* x  = (const float*)d_in[0];
    const float* Wc = (const float*)d_in[1];
    const float* bc = (const float*)d_in[2];
    const float* Wf = (const float*)d_in[3];
    const float* bf = (const float*)d_in[4];
    float* out = (float*)d_out;

    char* ws = (char*)d_ws;
    const size_t h_bytes = (size_t)BB * HH * WW * HIDDEN * 2;   // 16.78 MB
    const size_t c_bytes = (size_t)BB * HH * WW * HIDDEN * 4;   // 33.55 MB
    const size_t w_bytes = 9 * 4 * 64 * 8 * 2;                  // 36.9 KB
    const size_t f_bytes = (size_t)NTILES * 4;                  // 8 KB flags
    const size_t x_bytes = (size_t)BB * TT * HH * WW * 8 * 2;   // 100.7 MB

    unsigned short* h_a = (unsigned short*)(ws);
    unsigned short* h_b = (unsigned short*)(ws + h_bytes);
    float* c            = (float*)(ws + 2 * h_bytes);
    unsigned short* Wfr = (unsigned short*)(ws + 2 * h_bytes + c_bytes);
    unsigned int* flags = (unsigned int*)(ws + 2 * h_bytes + c_bytes + w_bytes);
    unsigned short* xp  = (unsigned short*)(ws + 2 * h_bytes + c_bytes + w_bytes + f_bytes);

    const int use_xp =
        (ws_size >= 2 * h_bytes + c_bytes + w_bytes + f_bytes + x_bytes) ? 1 : 0;

    prep_w_kernel<<<(9 * 4 * 64 * 8 + 255) / 256, 256, 0, stream>>>(Wc, Wfr);
    prep_flags_kernel<<<(NTILES + 255) / 256, 256, 0, stream>>>(flags);
    if (use_xp) {
        size_t totpx = (size_t)BB * TT * HH * WW;
        prep_x_kernel<<<(int)((totpx + 255) / 256), 256, 0, stream>>>(x, xp);
    }

    // Preferred path: persistent cooperative kernel with tile flags.
    int occ = 0;
    hipOccupancyMaxActiveBlocksPerMultiprocessor(&occ, convlstm_persistent_kernel,
                                                 256, 0);
    bool done = false;
    if (occ >= 4) {
        const unsigned short* xp_arg = use_xp ? xp : (const unsigned short*)0;
        int use_xp_arg = use_xp;
        void* kargs[] = {
            (void*)&x, (void*)&xp_arg, (void*)&h_a, (void*)&h_b,
            (void*)&Wfr, (void*)&bc, (void*)&Wf, (void*)&bf,
            (void*)&out, (void*)&flags, (void*)&use_xp_arg
        };
        if (hipLaunchCooperativeKernel((const void*)convlstm_persistent_kernel,
                                       dim3(NBLK_PERSIST, 1, 1), dim3(256, 1, 1),
                                       kargs, 0, stream) == hipSuccess)
            done = true;
    }

    if (!done) {
        // Legacy per-step path (round-0 behavior)
        dim3 grid(WW / TX, HH / TY, BB);   // 2048 blocks
        dim3 block(256, 1, 1);
        const unsigned short* h_in = h_a;
        for (int t = 0; t < TT; ++t) {
            unsigned short* h_out = (t & 1) ? h_b : h_a;
            convlstm_step_kernel<<<grid, block, 0, stream>>>(
                x, t, use_xp ? xp : (const unsigned short*)0,
                h_in, h_out, c, Wfr, bc, (t == 0) ? 1 : 0, use_xp);
            h_in = h_out;
        }
        final_conv_kernel<<<(BB * HH * WW + 255) / 256, 256, 0, stream>>>(
            h_in, Wf, bf, out);
    }
}

// Round 4
// 688.725 us; speedup vs baseline: 1.0169x; 1.0169x over previous
//
#include <hip/hip_runtime.h>
#include <math.h>

#define HIDDEN 16
#define CIN 5
#define BB 8
#define TT 12
#define HH 256
#define WW 256
#define TX 32
#define TY 8
#define HALO_X 34
#define HALO_Y 10
#define NPX (HALO_X * HALO_Y)   // 340 staged pixels
#define STRIDE 40               // legacy kernel only
#define NBLK_PERSIST 1024       // 4 blocks/CU x 256 CU; each owns 2 tiles
#define NTILES 2048
#define NRING 84                // halo ring pixels: 2*34 + 2*8
#define ROWSH 24                // shorts per LDS row: h[16] | x[8]  (48 B)
#define XSTEP (HH * WW * 8)     // xp shorts per t-slice per batch

typedef __attribute__((ext_vector_type(8))) short bf16x8;   // 8 bf16 (4 VGPRs)
typedef __attribute__((ext_vector_type(4))) float floatx4;

__device__ __forceinline__ unsigned short f2bf(float f) {   // RNE fp32->bf16
    unsigned int u = __float_as_uint(f);
    u += 0x7fffu + ((u >> 16) & 1u);
    return (unsigned short)(u >> 16);
}
__device__ __forceinline__ float bf2f(unsigned short s) {
    return __uint_as_float(((unsigned int)s) << 16);
}
__device__ __forceinline__ float rcpf(float x) {            // v_rcp_f32 (~1 ulp)
    float r;
    asm("v_rcp_f32 %0, %1" : "=v"(r) : "v"(x));
    return r;
}
__device__ __forceinline__ float fast_sigmoid(float x) {
    return rcpf(1.0f + __expf(-x));
}
__device__ __forceinline__ float fast_tanh(float x) {
    float e2 = __expf(-2.0f * fabsf(x));
    float t = (1.0f - e2) * rcpf(1.0f + e2);
    return copysignf(t, x);
}
// legacy-path gates (div-based, proven)
__device__ __forceinline__ float leg_sigmoid(float x) { return 1.0f / (1.0f + __expf(-x)); }
__device__ __forceinline__ float leg_tanh(float x) {
    float e2 = __expf(-2.0f * fabsf(x));
    float t = (1.0f - e2) / (1.0f + e2);
    return copysignf(t, x);
}

// Pack W_cell [64][21][3][3] into exact B-fragment layout for
// mfma_f32_16x16x32_bf16: Wfrag[tap][gate][lane][j]; lane holds
// B[k=(lane>>4)*8+j][col=lane&15], col = hidden unit, N-tile = gate.
// k-order: 0..15 = h units (ci_ref 5+k), 16..20 = x chans, 21..31 = 0.
__global__ void prep_w_kernel(const float* __restrict__ Wc,
                              unsigned short* __restrict__ Wfrag) {
    int i = blockIdx.x * 256 + threadIdx.x;
    if (i >= 9 * 4 * 64 * 8) return;
    int j    = i & 7;
    int lane = (i >> 3) & 63;
    int g    = (i >> 9) & 3;
    int tap  = i >> 11;
    int k    = ((lane >> 4) << 3) + j;
    int col  = lane & 15;
    int o    = g * 16 + col;
    float w  = 0.0f;
    if (k < 21) {
        int ci_ref = (k < 16) ? (5 + k) : (k - 16);
        w = Wc[(o * 21 + ci_ref) * 9 + tap];
    }
    Wfrag[i] = f2bf(w);
}

// One-time x repack: planar fp32 [b][t][c][y][x] -> channel-last bf16 [b][t][y][x][8]
__global__ void prep_x_kernel(const float* __restrict__ x,
                              unsigned short* __restrict__ xp) {
    size_t n = (size_t)blockIdx.x * 256 + threadIdx.x;
    const size_t TOTPX = (size_t)BB * TT * HH * WW;
    if (n >= TOTPX) return;
    size_t bt  = n / (size_t)(HH * WW);
    size_t pix = n - bt * (size_t)(HH * WW);
    const float* src = x + bt * (size_t)CIN * HH * WW + pix;
    unsigned short v[8];
    #pragma unroll
    for (int c = 0; c < CIN; ++c) v[c] = f2bf(src[(size_t)c * HH * WW]);
    v[5] = 0; v[6] = 0; v[7] = 0;
    *(uint4*)&xp[n * 8] = *(const uint4*)v;
}

__global__ void prep_flags_kernel(unsigned int* __restrict__ flags) {
    int i = blockIdx.x * 256 + threadIdx.x;
    if (i < NTILES) flags[i] = 0;
}

// ---------------------------------------------------------------------------
// Persistent kernel with h resident in LDS.
// LDS per block: 2 tile regions [NPX][24sh] (row = h16|x8, 48 B) + 8sh zero pad.
// Per tile-step: stage 84-px h ring from global + ds_write prefetched x;
// MFMA A-frag per quad: q0/q1 -> h bytes, q2 -> x bytes, q3 -> zero pad.
// Epilogue: gates (rcp-based), c in registers, h interior -> LDS,
// h ring (76 px) -> global for neighbors; flags protocol as round 3.
// Tile map: block bid (XCD = bid&7 round-robin) owns tiles of batch (bid&7):
// n = (bid&7)*256 + (bid>>3) + tl*128  -> all neighbor traffic same-XCD L2.
// ---------------------------------------------------------------------------
__global__ __launch_bounds__(256, 4)
void convlstm_persistent_kernel(const float* __restrict__ x,
                                const unsigned short* __restrict__ xp,  // may be null
                                unsigned short* __restrict__ ha,
                                unsigned short* __restrict__ hbuf,
                                const unsigned short* __restrict__ Wfrag,
                                const float* __restrict__ bias,
                                const float* __restrict__ Wf,
                                const float* __restrict__ bfin,
                                float* __restrict__ out,
                                unsigned int* __restrict__ flags,
                                int use_xp) {
    __shared__ unsigned short hx[2 * NPX * ROWSH + 8];   // 32656 B
    const int ZOFF = 2 * NPX * ROWSH;                    // zero-pad row (shorts)

    const int tid  = threadIdx.x;
    const int lane = tid & 63;
    const int wave = tid >> 6;
    const int u    = lane & 15;
    const int quad = lane >> 4;
    const int bid  = (int)blockIdx.x;

    // ---- tile ids (XCD-chunked) ----
    int ntile[2], x0v[2], y0v[2], bbv[2];
    #pragma unroll
    for (int tl = 0; tl < 2; ++tl) {
        int n = (bid & 7) * 256 + (bid >> 3) + tl * 128;
        ntile[tl] = n;
        x0v[tl] = (n & 7) * TX;
        y0v[tl] = ((n >> 3) & 31) * TY;
        bbv[tl] = n >> 8;
    }

    // ---- neighbor ids (wave0 lanes 0..7 poll), per tl ----
    int nb_id[2];
    unsigned nb_act = 0;
    {
        int s  = lane + (lane >= 4 ? 1 : 0);      // skip center
        int dy = s / 3 - 1;
        int dx = s - (s / 3) * 3 - 1;
        #pragma unroll
        for (int tl = 0; tl < 2; ++tl) {
            int n  = ntile[tl];
            int tx = n & 7;
            int ty = (n >> 3) & 31;
            bool act = (lane < 8) && (tx + dx >= 0) && (tx + dx < 8)
                                  && (ty + dy >= 0) && (ty + dy < 32);
            nb_id[tl] = act ? (n + dy * 8 + dx) : 0;
            if (act) nb_act |= 1u << tl;
        }
    }

    // ---- x staging descriptors (rows tid, tid+256) ----
    int xof[2][2];      // shorts offset into xp at t=0 (+ t*XSTEP per step)
    int pixv[2][2];     // pixel index (for !use_xp path)
    unsigned inbm = 0;
    #pragma unroll
    for (int tl = 0; tl < 2; ++tl) {
        #pragma unroll
        for (int it = 0; it < 2; ++it) {
            int i  = tid + it * 256;
            int ly = i / HALO_X;
            int lx = i - ly * HALO_X;
            int gy = y0v[tl] + ly - 1;
            int gx = x0v[tl] + lx - 1;
            bool inb = (gy >= 0 && gy < HH && gx >= 0 && gx < WW) && (i < NPX);
            int pix = gy * WW + gx;
            pixv[tl][it] = pix;
            xof[tl][it]  = (bbv[tl] * TT * HH * WW + pix) * 8;
            if (inb) inbm |= 1u << (tl * 2 + it);
        }
    }

    // ---- ring descriptors (tid < 84) ----
    int rrow = 0;
    int rgoff[2] = {0, 0};
    unsigned ringm = 0;
    if (tid < NRING) {
        int ly, lx;
        if (tid < 34)      { ly = 0;                lx = tid; }
        else if (tid < 68) { ly = HALO_Y - 1;       lx = tid - 34; }
        else { int k = tid - 68; ly = 1 + (k >> 1); lx = (k & 1) * (HALO_X - 1); }
        rrow = ly * HALO_X + lx;
        #pragma unroll
        for (int tl = 0; tl < 2; ++tl) {
            int gy = y0v[tl] + ly - 1;
            int gx = x0v[tl] + lx - 1;
            bool inb = (gy >= 0 && gy < HH && gx >= 0 && gx < WW);
            rgoff[tl] = (bbv[tl] * HH * WW + gy * WW + gx) * HIDDEN;
            if (inb) ringm |= 1u << tl;
        }
    }

    // ---- prologue: issue x prefetch for (t=0, tl=0) ----
    uint4 xr0 = {0, 0, 0, 0}, xr1 = {0, 0, 0, 0};
    if (use_xp) {
        if (inbm & 1u) xr0 = *(const uint4*)&xp[xof[0][0]];
        if (tid < NPX - 256 && (inbm & 2u)) xr1 = *(const uint4*)&xp[xof[0][1]];
    }

    // ---- init: zero h-part of both regions + zero pad ----
    for (int i = tid; i < 2 * NPX; i += 256) {
        uint4 z = {0, 0, 0, 0};
        *(uint4*)&hx[i * ROWSH]     = z;
        *(uint4*)&hx[i * ROWSH + 8] = z;
    }
    if (tid == 0) { uint4 z = {0, 0, 0, 0}; *(uint4*)&hx[ZOFF] = z; }

    float bg[4];
    #pragma unroll
    for (int g = 0; g < 4; ++g) bg[g] = bias[g * 16 + u];
    const float wfu = Wf[u];
    const float bf0 = bfin[0];
    const int msel  = (quad < 3) ? ROWSH : 0;   // af row stride select (q3 -> 0)

    // c-state registers: [tl][mh][r] per half (static indexing only)
    float cA[2][2][4];
    float cB[2][2][4];
    #pragma unroll
    for (int a = 0; a < 2; ++a)
        #pragma unroll
        for (int m = 0; m < 2; ++m)
            #pragma unroll
            for (int r = 0; r < 4; ++r) { cA[a][m][r] = 0.0f; cB[a][m][r] = 0.0f; }

    #pragma unroll 1
    for (int t = 0; t < TT; ++t) {
        const unsigned short* h_in  = (t & 1) ? ha : hbuf;
        unsigned short*       h_out = (t & 1) ? hbuf : ha;
        const int first = (t == 0);
        const int last  = (t == TT - 1);

        #pragma unroll
        for (int tl = 0; tl < 2; ++tl) {
            const int n   = ntile[tl];
            const int x0  = x0v[tl];
            const int y0  = y0v[tl];
            const int bb  = bbv[tl];
            const int TLB = tl * NPX * ROWSH;

            // ---- (A) wait for 8 neighbors to have completed step t-1 ----
            if (t > 0) {
                if (wave == 0) {
                    const bool act = (nb_act >> tl) & 1;
                    const unsigned need = (unsigned)t;
                    for (;;) {
                        unsigned v = act
                            ? __hip_atomic_load(&flags[nb_id[tl]], __ATOMIC_RELAXED,
                                                __HIP_MEMORY_SCOPE_AGENT)
                            : 0xFFFFFFFFu;
                        if (__all(v >= need)) break;
                        __builtin_amdgcn_s_sleep(2);
                    }
                    if (tid == 0) __threadfence();   // acquire: inv L1
                }
                __syncthreads();
            }

            // ---- (B) stage: x (prefetched) + h halo ring ----
            if (use_xp) {
                *(uint4*)&hx[TLB + tid * ROWSH + 16] = xr0;
                if (tid < NPX - 256)
                    *(uint4*)&hx[TLB + (tid + 256) * ROWSH + 16] = xr1;
            } else {
                #pragma unroll
                for (int it = 0; it < 2; ++it) {
                    if (it == 1 && tid >= NPX - 256) break;
                    const bool inb = (inbm >> (tl * 2 + it)) & 1;
                    unsigned short v[8];
                    #pragma unroll
                    for (int ci = 0; ci < CIN; ++ci) {
                        float f = 0.0f;
                        if (inb) f = x[(((size_t)bb * TT + t) * CIN + ci) * (size_t)(HH * WW)
                                       + pixv[tl][it]];
                        v[ci] = f2bf(f);
                    }
                    v[5] = 0; v[6] = 0; v[7] = 0;
                    *(uint4*)&hx[TLB + (tid + it * 256) * ROWSH + 16] = *(const uint4*)v;
                }
            }
            if (!first && tid < NRING && ((ringm >> tl) & 1)) {
                const unsigned short* hp = h_in + rgoff[tl];
                *(uint4*)&hx[TLB + rrow * ROWSH]     = *(const uint4*)&hp[0];
                *(uint4*)&hx[TLB + rrow * ROWSH + 8] = *(const uint4*)&hp[8];
            }
            // issue prefetch for next tile-visit
            if (use_xp) {
                const int ntl = tl ^ 1;
                const int nt  = t + tl;          // tl=0 -> (t, 1); tl=1 -> (t+1, 0)
                if (nt < TT) {
                    uint4 z4 = {0, 0, 0, 0};
                    xr0 = ((inbm >> (ntl * 2)) & 1)
                        ? *(const uint4*)&xp[xof[ntl][0] + nt * XSTEP] : z4;
                    if (tid < NPX - 256)
                        xr1 = ((inbm >> (ntl * 2 + 1)) & 1)
                            ? *(const uint4*)&xp[xof[ntl][1] + nt * XSTEP] : z4;
                }
            }
            __syncthreads();   // (C)

            // ---- (D) compute: 2 halves of 2 M-strips each ----
            #pragma unroll 1
            for (int half = 0; half < 2; ++half) {
                floatx4 acc[2][4];
                int A[2];
                #pragma unroll
                for (int mh = 0; mh < 2; ++mh) {
                    int ml = half * 2 + mh;
                    int m  = wave + ml * 4;
                    int my = m >> 1;
                    int mx = (m & 1) << 4;
                    int bpx = my * HALO_X + mx + u;
                    A[mh] = (quad < 3) ? (TLB + bpx * ROWSH + quad * 8) : ZOFF;
                    #pragma unroll
                    for (int g = 0; g < 4; ++g)
                        acc[mh][g] = (floatx4){bg[g], bg[g], bg[g], bg[g]};
                }

                #pragma unroll 3
                for (int tap = 0; tap < 9; ++tap) {
                    int ky = tap / 3;
                    int kx = tap - ky * 3;
                    int ktap = ky * HALO_X + kx;
                    bf16x8 bfr[4];
                    #pragma unroll
                    for (int g = 0; g < 4; ++g)
                        bfr[g] = *(const bf16x8*)&Wfrag[(size_t)((tap * 4 + g) * 64 + lane) * 8];
                    #pragma unroll
                    for (int mh = 0; mh < 2; ++mh) {
                        bf16x8 af = *(const bf16x8*)&hx[A[mh] + ktap * msel];
                        #pragma unroll
                        for (int g = 0; g < 4; ++g)
                            acc[mh][g] = __builtin_amdgcn_mfma_f32_16x16x32_bf16(
                                af, bfr[g], acc[mh][g], 0, 0, 0);
                    }
                }

                // ---- epilogue ----
                #pragma unroll
                for (int mh = 0; mh < 2; ++mh) {
                    int ml = half * 2 + mh;
                    int m  = wave + ml * 4;
                    int my = m >> 1;
                    int mx = (m & 1) << 4;
                    int py = y0 + my;
                    int col0 = mx + quad * 4;
                    int erow = (my + 1) * HALO_X + col0 + 1;
                    int eaddr = TLB + erow * ROWSH + u;
                    size_t gidx0 = ((size_t)bb * HH * WW + (size_t)py * WW + x0 + col0)
                                   * HIDDEN + u;
                    bool topbot = (my == 0) || (my == TY - 1);
                    #pragma unroll
                    for (int r = 0; r < 4; ++r) {
                        float ig = fast_sigmoid(acc[mh][0][r]);
                        float fg = fast_sigmoid(acc[mh][1][r]);
                        float og = fast_sigmoid(acc[mh][2][r]);
                        float gg = fast_tanh(acc[mh][3][r]);
                        float c_old = half ? cB[tl][mh][r] : cA[tl][mh][r];
                        float c_new = fg * c_old + ig * gg;
                        if (half) cB[tl][mh][r] = c_new; else cA[tl][mh][r] = c_new;
                        float hval = og * fast_tanh(c_new);
                        if (last) {
                            // fused 1x1 conv: sum over 16 channels (u lanes)
                            float s = wfu * hval;
                            s += __shfl_xor(s, 1);
                            s += __shfl_xor(s, 2);
                            s += __shfl_xor(s, 4);
                            s += __shfl_xor(s, 8);
                            int col = col0 + r;
                            if (u == 0)
                                out[(size_t)bb * HH * WW + (size_t)py * WW + x0 + col]
                                    = s + bf0;
                        } else {
                            unsigned short hs = f2bf(hval);
                            hx[eaddr + r * ROWSH] = hs;           // interior -> LDS
                            int col = col0 + r;
                            if (topbot || col == 0 || col == TX - 1)
                                h_out[gidx0 + (size_t)r * HIDDEN] = hs;  // ring -> global
                        }
                    }
                }
            }

            // ---- (E) publish ----
            if (!last) {
                __syncthreads();   // drains vmcnt before barrier
                if (tid == 0) {
                    __threadfence();   // release
                    __hip_atomic_store(&flags[n], (unsigned)(t + 1), __ATOMIC_RELAXED,
                                       __HIP_MEMORY_SCOPE_AGENT);
                }
            }
        }
    }
}

// ---------------------------------------------------------------------------
// Legacy per-step path (round-0, proven) — fallback if cooperative launch
// is unavailable.
// ---------------------------------------------------------------------------
__global__ __launch_bounds__(256, 5)
void convlstm_step_kernel(const float* __restrict__ x, int t,
                          const unsigned short* __restrict__ xp,  // may be null
                          const unsigned short* __restrict__ h_in,
                          unsigned short* __restrict__ h_out,
                          float* __restrict__ c_state,
                          const unsigned short* __restrict__ Wfrag,
                          const float* __restrict__ bias,
                          int first, int use_xp) {
    __shared__ unsigned short tile[NPX * STRIDE];   // 27200 B

    const int tid  = threadIdx.x;
    const int lane = tid & 63;
    const int wave = tid >> 6;
    const int x0 = blockIdx.x * TX;
    const int y0 = blockIdx.y * TY;
    const int bb = blockIdx.z;

    for (int i = tid; i < NPX; i += 256) {
        int ly = i / HALO_X;
        int lx = i - ly * HALO_X;
        int gy = y0 + ly - 1;
        int gx = x0 + lx - 1;
        bool inb = (gy >= 0 && gy < HH && gx >= 0 && gx < WW);
        unsigned short* row = &tile[i * STRIDE];
        uint4 z = {0, 0, 0, 0};
        if (inb && !first) {
            size_t hbase = ((size_t)bb * HH * WW + (size_t)gy * WW + gx) * HIDDEN;
            *(uint4*)&row[0] = *(const uint4*)&h_in[hbase];
            *(uint4*)&row[8] = *(const uint4*)&h_in[hbase + 8];
        } else {
            *(uint4*)&row[0] = z;
            *(uint4*)&row[8] = z;
        }
        if (use_xp) {
            if (inb) {
                size_t xb = (((size_t)bb * TT + t) * (size_t)(HH * WW)
                             + (size_t)gy * WW + gx) * 8;
                *(uint4*)&row[16] = *(const uint4*)&xp[xb];
            } else {
                *(uint4*)&row[16] = z;
            }
        } else {
            #pragma unroll
            for (int ci = 0; ci < CIN; ++ci) {
                float v = 0.0f;
                if (inb) v = x[(((size_t)bb * TT + t) * CIN + ci) * (size_t)(HH * WW)
                               + (size_t)gy * WW + gx];
                row[16 + ci] = f2bf(v);
            }
            row[21] = 0; row[22] = 0; row[23] = 0;
        }
        *(uint4*)&row[24] = z;
    }
    __syncthreads();

    const int u    = lane & 15;
    const int quad = lane >> 4;

    float bg[4];
    #pragma unroll
    for (int g = 0; g < 4; ++g) bg[g] = bias[g * 16 + u];

    #pragma unroll 1
    for (int half = 0; half < 2; ++half) {
        floatx4 acc[2][4];
        int abase[2];
        #pragma unroll
        for (int mh = 0; mh < 2; ++mh) {
            int ml = half * 2 + mh;
            int m  = wave + ml * 4;
            int my = m >> 1;
            int mx = (m & 1) << 4;
            abase[mh] = (my * HALO_X + mx + u) * STRIDE + quad * 8;
            #pragma unroll
            for (int g = 0; g < 4; ++g)
                acc[mh][g] = (floatx4){bg[g], bg[g], bg[g], bg[g]};
        }

        #pragma unroll 3
        for (int tap = 0; tap < 9; ++tap) {
            int ky = tap / 3;
            int kx = tap - ky * 3;
            int toff = (ky * HALO_X + kx) * STRIDE;
            bf16x8 bfr[4];
            #pragma unroll
            for (int g = 0; g < 4; ++g)
                bfr[g] = *(const bf16x8*)&Wfrag[(size_t)((tap * 4 + g) * 64 + lane) * 8];
            #pragma unroll
            for (int mh = 0; mh < 2; ++mh) {
                bf16x8 af = *(const bf16x8*)&tile[abase[mh] + toff];
                #pragma unroll
                for (int g = 0; g < 4; ++g)
                    acc[mh][g] = __builtin_amdgcn_mfma_f32_16x16x32_bf16(
                        af, bfr[g], acc[mh][g], 0, 0, 0);
            }
        }

        #pragma unroll
        for (int mh = 0; mh < 2; ++mh) {
            int ml = half * 2 + mh;
            int m  = wave + ml * 4;
            int my = m >> 1;
            int mx = (m & 1) << 4;
            int py = y0 + my;
            #pragma unroll
            for (int r = 0; r < 4; ++r) {
                int pxx = x0 + mx + quad * 4 + r;
                size_t idx = ((size_t)bb * HH * WW + (size_t)py * WW + pxx) * HIDDEN + u;
                float ig = leg_sigmoid(acc[mh][0][r]);
                float fg = leg_sigmoid(acc[mh][1][r]);
                float og = leg_sigmoid(acc[mh][2][r]);
                float gg = leg_tanh(acc[mh][3][r]);
                float c_old = first ? 0.0f : c_state[idx];
                float c_new = fg * c_old + ig * gg;
                c_state[idx] = c_new;
                h_out[idx] = f2bf(og * leg_tanh(c_new));
            }
        }
    }
}

// Final 1x1 conv from bf16 channel-last h (legacy path only)
__global__ void final_conv_kernel(const unsigned short* __restrict__ h,
                                  const float* __restrict__ Wf,
                                  const float* __restrict__ bf_,
                                  float* __restrict__ out) {
    int i = blockIdx.x * 256 + threadIdx.x;
    if (i >= BB * HH * WW) return;
    size_t base = (size_t)i * HIDDEN;
    uint4 v0 = *(const uint4*)&h[base];
    uint4 v1 = *(const uint4*)&h[base + 8];
    const unsigned short* p0 = (const unsigned short*)&v0;
    const unsigned short* p1 = (const unsigned short*)&v1;
    float s = bf_[0];
    #pragma unroll
    for (int k = 0; k < 8; ++k) s += Wf[k] * bf2f(p0[k]);
    #pragma unroll
    for (int k = 0; k < 8; ++k) s += Wf[8 + k] * bf2f(p1[k]);
    out[i] = s;
}

extern "C" void kernel_launch(void* const* d_in, const int* in_sizes, int n_in,
                              void* d_out, int out_size, void* d_ws, size_t ws_size,
                              hipStream_t stream) {
    const float* x  = (const float*)d_in[0];
    const float* Wc = (const float*)d_in[1];
    const float* bc = (const float*)d_in[2];
    const float* Wf = (const float*)d_in[3];
    const float* bf = (const float*)d_in[4];
    float* out = (float*)d_out;

    char* ws = (char*)d_ws;
    const size_t h_bytes = (size_t)BB * HH * WW * HIDDEN * 2;   // 16.78 MB
    const size_t c_bytes = (size_t)BB * HH * WW * HIDDEN * 4;   // 33.55 MB
    const size_t w_bytes = 9 * 4 * 64 * 8 * 2;                  // 36.9 KB
    const size_t f_bytes = (size_t)NTILES * 4;                  // 8 KB flags
    const size_t x_bytes = (size_t)BB * TT * HH * WW * 8 * 2;   // 100.7 MB

    unsigned short* h_a = (unsigned short*)(ws);
    unsigned short* h_b = (unsigned short*)(ws + h_bytes);
    float* c            = (float*)(ws + 2 * h_bytes);
    unsigned short* Wfr = (unsigned short*)(ws + 2 * h_bytes + c_bytes);
    unsigned int* flags = (unsigned int*)(ws + 2 * h_bytes + c_bytes + w_bytes);
    unsigned short* xp  = (unsigned short*)(ws + 2 * h_bytes + c_bytes + w_bytes + f_bytes);

    const int use_xp =
        (ws_size >= 2 * h_bytes + c_bytes + w_bytes + f_bytes + x_bytes) ? 1 : 0;

    prep_w_kernel<<<(9 * 4 * 64 * 8 + 255) / 256, 256, 0, stream>>>(Wc, Wfr);
    prep_flags_kernel<<<(NTILES + 255) / 256, 256, 0, stream>>>(flags);
    if (use_xp) {
        size_t totpx = (size_t)BB * TT * HH * WW;
        prep_x_kernel<<<(int)((totpx + 255) / 256), 256, 0, stream>>>(x, xp);
    }

    // Preferred path: persistent kernel (h in LDS, c in registers).
    int occ = 0;
    hipOccupancyMaxActiveBlocksPerMultiprocessor(&occ, convlstm_persistent_kernel,
                                                 256, 0);
    bool done = false;
    if (occ >= 4) {
        const unsigned short* xp_arg = use_xp ? xp : (const unsigned short*)0;
        int use_xp_arg = use_xp;
        void* kargs[] = {
            (void*)&x, (void*)&xp_arg, (void*)&h_a, (void*)&h_b,
            (void*)&Wfr, (void*)&bc, (void*)&Wf, (void*)&bf,
            (void*)&out, (void*)&flags, (void*)&use_xp_arg
        };
        if (hipLaunchCooperativeKernel((const void*)convlstm_persistent_kernel,
                                       dim3(NBLK_PERSIST, 1, 1), dim3(256, 1, 1),
                                       kargs, 0, stream) == hipSuccess)
            done = true;
    }

    if (!done) {
        // Legacy per-step path (round-0 behavior)
        dim3 grid(WW / TX, HH / TY, BB);   // 2048 blocks
        dim3 block(256, 1, 1);
        const unsigned short* h_in = h_a;
        for (int t = 0; t < TT; ++t) {
            unsigned short* h_out = (t & 1) ? h_b : h_a;
            convlstm_step_kernel<<<grid, block, 0, stream>>>(
                x, t, use_xp ? xp : (const unsigned short*)0,
                h_in, h_out, c, Wfr, bc, (t == 0) ? 1 : 0, use_xp);
            h_in = h_out;
        }
        final_conv_kernel<<<(BB * HH * WW + 255) / 256, 256, 0, stream>>>(
            h_in, Wf, bf, out);
    }
}